// Round 4
// baseline (458.834 us; speedup 1.0000x reference)
//
#include <hip/hip_runtime.h>
#include <cstddef>

#define N_    2048
#define H_    32
#define NEGF  (-1.0e30f)
#define LOG2E 1.4426950408889634f
#define C1F   (0.17677669529663687f * 1.4426950408889634f)   // (1/sqrt(32))*log2e
#define DEFER 8.0f

__device__ __forceinline__ float exp2_fast(float x) {
    float r;
    asm("v_exp_f32 %0, %1" : "=v"(r) : "v"(x));
    return r;
}

// ---------------------------------------------------------------- init h
__global__ __launch_bounds__(256) void k_init_h(const float* __restrict__ feats,
                                                const float* __restrict__ W_in,
                                                float* __restrict__ h) {
    int idx = blockIdx.x * 256 + threadIdx.x;       // B*N*32 total
    int bn  = idx >> 5, c = idx & 31;
    float f0 = feats[bn * 3 + 0], f1 = feats[bn * 3 + 1], f2 = feats[bn * 3 + 2];
    h[idx] = f0 * W_in[c] + f1 * W_in[32 + c] + f2 * W_in[64 + c];
}

// ---------------------------------------------------------------- q,k,v
__global__ __launch_bounds__(256) void k_qkv(const float* __restrict__ h,
                                             const float* __restrict__ Wq,
                                             const float* __restrict__ Wk,
                                             const float* __restrict__ Wv,
                                             float* __restrict__ q,
                                             float* __restrict__ k,
                                             float* __restrict__ v) {
    __shared__ float hs[8][33];
    int t = threadIdx.x;
    int rl = t >> 5, c = t & 31;
    int row = blockIdx.x * 8 + rl;
    hs[rl][c] = h[(row << 5) + c];
    __syncthreads();
    float aq = 0.f, ak = 0.f, av = 0.f;
#pragma unroll
    for (int d = 0; d < 32; ++d) {
        float hd = hs[rl][d];
        aq += hd * Wq[(d << 5) + c];
        ak += hd * Wk[(d << 5) + c];
        av += hd * Wv[(d << 5) + c];
    }
    q[(row << 5) + c] = aq;
    k[(row << 5) + c] = ak;
    v[(row << 5) + c] = av;
}

// ---------------------------------------------------------------- fused attention + post + FF
__device__ __forceinline__ void finish_row(float (&acc)[35], float m, float s,
                                           float xi0, float xi1, float xi2,
                                           int lane, int row, float cs,
                                           float* __restrict__ hg,
                                           float* __restrict__ xout,
                                           const float* __restrict__ Wo,
                                           const float* __restrict__ W1,
                                           const float* __restrict__ W2,
                                           float* __restrict__ h1row,
                                           float* __restrict__ frow) {
    // cross-lane online-softmax merge (m is in log2 domain)
    float mm = m;
#pragma unroll
    for (int off = 32; off > 0; off >>= 1) mm = fmaxf(mm, __shfl_xor(mm, off));
    float sc = exp2_fast(m - mm);
    float ss = s * sc;
#pragma unroll
    for (int c = 0; c < 35; ++c) acc[c] *= sc;
#pragma unroll
    for (int off = 32; off > 0; off >>= 1) {
        ss += __shfl_xor(ss, off);
#pragma unroll
        for (int c = 0; c < 35; ++c) acc[c] += __shfl_xor(acc[c], off);
    }
    float rinv = 1.0f / ss;
    int rb = row << 5;
    float h1 = 0.f;
    if (lane < 32) {
        float hv = 0.f;
#pragma unroll
        for (int d = 0; d < 32; ++d) hv += acc[d] * Wo[(d << 5) + lane];
        h1 = hg[rb + lane] + hv * rinv;
        h1row[lane] = h1;
    }
    float ff = 0.f;                       // all 64 lanes: FF hidden dim 64
#pragma unroll
    for (int d = 0; d < 32; ++d) ff += h1row[d] * W1[(d << 6) + lane];
    frow[lane] = fmaxf(ff, 0.f);
    if (lane < 32) {
        float v2 = 0.f;
#pragma unroll
        for (int u = 0; u < 64; ++u) v2 += frow[u] * W2[(u << 5) + lane];
        hg[rb + lane] = h1 + v2;
    }
    if (lane < 3) {
        float ox = (lane == 0 ? acc[32] : (lane == 1 ? acc[33] : acc[34])) * rinv;
        float xi = (lane == 0 ? xi0 : (lane == 1 ? xi1 : xi2));
        xout[row * 3 + lane] = xi + cs * (xi - ox);
    }
}

// 16 rows/block, 8 waves of 2 rows. Each wave stages 8 rows (1KB) of K and V
// per tile: LDS dest wave-uniform base + lane*16 (linear), global source
// pre-swizzled (row r position p <- chunk p^(r&7)); reads use the same XOR.
__global__ __launch_bounds__(512) void k_attn(const float* __restrict__ qg,
                                              const float* __restrict__ kg,
                                              const float* __restrict__ vg,
                                              float* __restrict__ hg,
                                              const float* __restrict__ xin,
                                              float* __restrict__ xout,
                                              const int* __restrict__ adj,
                                              const float* __restrict__ Wo,
                                              const float* __restrict__ W1,
                                              const float* __restrict__ W2,
                                              const float* __restrict__ csp) {
    __shared__ __attribute__((aligned(16))) float k_s[2][64 * 32];
    __shared__ __attribute__((aligned(16))) float v_s[2][64 * 32];
    __shared__ float h1_s[8][33];
    __shared__ float f_s[8][64];

    const int t = threadIdx.x;
    const int w = t >> 6, lane = t & 63;
    const int b  = blockIdx.x >> 7;            // 128 blocks per batch
    const int ib = (blockIdx.x & 127) << 4;    // 16 rows per block
    const int bN = b << 11;
    const int row0 = bN + ib + (w << 1), row1 = row0 + 1;
    const float cs = csp[0];

    // staging geometry (constant per thread): wave stages rows 8w..8w+7
    const int sr = (w << 3) + (lane >> 3);          // tile row 0..63
    const int sc_ = (lane & 7) ^ (sr & 7);          // swizzled source chunk
    const float* krun = kg + ((size_t)(bN + sr) << 5) + (sc_ << 2);
    const float* vrun = vg + ((size_t)(bN + sr) << 5) + (sc_ << 2);
    const int dstoff = w << 10;                     // byte offset of wave's 1KB

    // q rows, pre-scaled by (1/sqrt(d))*log2e
    float q0[32], q1[32];
#pragma unroll
    for (int d = 0; d < 32; d += 4) {
        float4 a = *(const float4*)(qg + ((size_t)row0 << 5) + d);
        q0[d] = a.x * C1F; q0[d + 1] = a.y * C1F; q0[d + 2] = a.z * C1F; q0[d + 3] = a.w * C1F;
        float4 b4 = *(const float4*)(qg + ((size_t)row1 << 5) + d);
        q1[d] = b4.x * C1F; q1[d + 1] = b4.y * C1F; q1[d + 2] = b4.z * C1F; q1[d + 3] = b4.w * C1F;
    }
    const float xi00 = xin[row0 * 3 + 0], xi01 = xin[row0 * 3 + 1], xi02 = xin[row0 * 3 + 2];
    const float xi10 = xin[row1 * 3 + 0], xi11 = xin[row1 * 3 + 1], xi12 = xin[row1 * 3 + 2];
    const int* ap0 = adj + (size_t)row0 * N_ + lane;
    const int* ap1 = adj + (size_t)row1 * N_ + lane;
    const float* xp = xin + ((size_t)(bN + lane)) * 3;

    float acc0[35], acc1[35];
#pragma unroll
    for (int c = 0; c < 35; ++c) { acc0[c] = 0.f; acc1[c] = 0.f; }
    float m0 = NEGF, m1 = NEGF, sum0 = 0.f, sum1 = 0.f;

    const int kb = lane << 5;
    const int lx = lane & 7;

    // ---- prologue: stage tile 0 + its adj/x
    __builtin_amdgcn_global_load_lds((const __attribute__((address_space(1))) void*)krun,
                                     (__attribute__((address_space(3))) void*)((char*)&k_s[0][0] + dstoff), 16, 0, 0);
    __builtin_amdgcn_global_load_lds((const __attribute__((address_space(1))) void*)vrun,
                                     (__attribute__((address_space(3))) void*)((char*)&v_s[0][0] + dstoff), 16, 0, 0);
    krun += 2048; vrun += 2048;
    int a0c = *ap0, a1c = *ap1;
    ap0 += 64; ap1 += 64;
    float xj0 = xp[0], xj1 = xp[1], xj2 = xp[2];
    xp += 192;
    __syncthreads();

    int cur = 0;
    int a0n = 0, a1n = 0;
    float xan = 0.f, xbn = 0.f, xcn = 0.f;

    for (int jt = 0; jt < N_; jt += 64) {
        const bool hasNext = (jt + 64) < N_;
        if (hasNext) {
            __builtin_amdgcn_global_load_lds((const __attribute__((address_space(1))) void*)krun,
                                             (__attribute__((address_space(3))) void*)((char*)&k_s[cur ^ 1][0] + dstoff), 16, 0, 0);
            __builtin_amdgcn_global_load_lds((const __attribute__((address_space(1))) void*)vrun,
                                             (__attribute__((address_space(3))) void*)((char*)&v_s[cur ^ 1][0] + dstoff), 16, 0, 0);
            krun += 2048; vrun += 2048;
            a0n = *ap0; a1n = *ap1;
            ap0 += 64; ap1 += 64;
            xan = xp[0]; xbn = xp[1]; xcn = xp[2];
            xp += 192;
        }

        const float* ks = &k_s[cur][0];
        const float* vs = &v_s[cur][0];

        // QK dots with 4 partial accumulators per row (ILP)
        float p00 = 0.f, p01 = 0.f, p02 = 0.f, p03 = 0.f;
        float p10 = 0.f, p11 = 0.f, p12 = 0.f, p13 = 0.f;
#pragma unroll
        for (int c = 0; c < 8; ++c) {
            float4 k4 = *(const float4*)&ks[kb + ((c ^ lx) << 2)];
            p00 = fmaf(q0[4 * c],     k4.x, p00);
            p01 = fmaf(q0[4 * c + 1], k4.y, p01);
            p02 = fmaf(q0[4 * c + 2], k4.z, p02);
            p03 = fmaf(q0[4 * c + 3], k4.w, p03);
            p10 = fmaf(q1[4 * c],     k4.x, p10);
            p11 = fmaf(q1[4 * c + 1], k4.y, p11);
            p12 = fmaf(q1[4 * c + 2], k4.z, p12);
            p13 = fmaf(q1[4 * c + 3], k4.w, p13);
        }
        float dot0 = (p00 + p01) + (p02 + p03);
        float dot1 = (p10 + p11) + (p12 + p13);

        float d00 = xi00 - xj0, d01 = xi01 - xj1, d02 = xi02 - xj2;
        float d10 = xi10 - xj0, d11 = xi11 - xj1, d12 = xi12 - xj2;
        float t0 = fmaf(d02, d02, fmaf(d01, d01, d00 * d00));
        float t1 = fmaf(d12, d12, fmaf(d11, d11, d10 * d10));
        // logits in log2 domain (q pre-scaled)
        float se0 = a0c ? fmaf(t0, -LOG2E, dot0) : NEGF;
        float se1 = a1c ? fmaf(t1, -LOG2E, dot1) : NEGF;

        // T13: wave-uniform deferred-max rescale
        if (__any(int(se0 - m0 > DEFER) | int(se1 - m1 > DEFER))) {
            float n0 = fmaxf(m0, se0), n1 = fmaxf(m1, se1);
            float al0 = exp2_fast(m0 - n0), al1 = exp2_fast(m1 - n1);
            m0 = n0; m1 = n1;
            sum0 *= al0; sum1 *= al1;
#pragma unroll
            for (int c = 0; c < 35; ++c) { acc0[c] *= al0; acc1[c] *= al1; }
        }
        float p0 = exp2_fast(se0 - m0);
        float p1 = exp2_fast(se1 - m1);
        sum0 += p0; sum1 += p1;

#pragma unroll
        for (int c = 0; c < 8; ++c) {
            float4 v4 = *(const float4*)&vs[kb + ((c ^ lx) << 2)];
            acc0[4 * c]     = fmaf(p0, v4.x, acc0[4 * c]);
            acc0[4 * c + 1] = fmaf(p0, v4.y, acc0[4 * c + 1]);
            acc0[4 * c + 2] = fmaf(p0, v4.z, acc0[4 * c + 2]);
            acc0[4 * c + 3] = fmaf(p0, v4.w, acc0[4 * c + 3]);
            acc1[4 * c]     = fmaf(p1, v4.x, acc1[4 * c]);
            acc1[4 * c + 1] = fmaf(p1, v4.y, acc1[4 * c + 1]);
            acc1[4 * c + 2] = fmaf(p1, v4.z, acc1[4 * c + 2]);
            acc1[4 * c + 3] = fmaf(p1, v4.w, acc1[4 * c + 3]);
        }
        acc0[32] = fmaf(p0, xj0, acc0[32]);
        acc0[33] = fmaf(p0, xj1, acc0[33]);
        acc0[34] = fmaf(p0, xj2, acc0[34]);
        acc1[32] = fmaf(p1, xj0, acc1[32]);
        acc1[33] = fmaf(p1, xj1, acc1[33]);
        acc1[34] = fmaf(p1, xj2, acc1[34]);

        __syncthreads();   // publishes next-tile LDS (implicit vmcnt drain)
        cur ^= 1;
        a0c = a0n; a1c = a1n; xj0 = xan; xj1 = xbn; xj2 = xcn;
    }

    finish_row(acc0, m0, sum0, xi00, xi01, xi02, lane, row0, cs,
               hg, xout, Wo, W1, W2, &h1_s[w][0], &f_s[w][0]);
    finish_row(acc1, m1, sum1, xi10, xi11, xi12, lane, row1, cs,
               hg, xout, Wo, W1, W2, &h1_s[w][0], &f_s[w][0]);
}

// ---------------------------------------------------------------- pool + MLP head
__global__ __launch_bounds__(256) void k_final(const float* __restrict__ h,
                                               const float* __restrict__ Wf1,
                                               const float* __restrict__ bf1,
                                               const float* __restrict__ Wf2,
                                               const float* __restrict__ bf2,
                                               float* __restrict__ out) {
    int b = blockIdx.x, t = threadIdx.x;
    int c = t & 31, g = t >> 5;
    float s = 0.f;
    for (int n = g; n < N_; n += 8) s += h[(((b << 11) + n) << 5) + c];
    __shared__ float pool[8][32];
    __shared__ float pooled[32];
    __shared__ float a1[16];
    pool[g][c] = s;
    __syncthreads();
    if (t < 32) {
        float ss = 0.f;
#pragma unroll
        for (int gg = 0; gg < 8; ++gg) ss += pool[gg][t];
        pooled[t] = ss * (1.0f / N_);
    }
    __syncthreads();
    if (t < 16) {
        float a = bf1[t];
#pragma unroll
        for (int d = 0; d < 32; ++d) a += pooled[d] * Wf1[(d << 4) + t];
        a1[t] = fmaxf(a, 0.f);
    }
    __syncthreads();
    if (t < 3) {
        float o = bf2[t];
#pragma unroll
        for (int e = 0; e < 16; ++e) o += a1[e] * Wf2[e * 3 + t];
        out[b * 3 + t] = o;
    }
}

// ---------------------------------------------------------------- launch
extern "C" void kernel_launch(void* const* d_in, const int* in_sizes, int n_in,
                              void* d_out, int out_size, void* d_ws, size_t ws_size,
                              hipStream_t stream) {
    const float* feats = (const float*)d_in[0];
    const float* coors = (const float*)d_in[1];
    const int*   adj   = (const int*)d_in[2];
    const float* W_in  = (const float*)d_in[3];
    const float* Wq    = (const float*)d_in[4];
    const float* Wk    = (const float*)d_in[5];
    const float* Wv    = (const float*)d_in[6];
    const float* Wo    = (const float*)d_in[7];
    const float* W1    = (const float*)d_in[8];
    const float* W2    = (const float*)d_in[9];
    const float* csc   = (const float*)d_in[10];
    const float* Wf1   = (const float*)d_in[11];
    const float* bf1   = (const float*)d_in[12];
    const float* Wf2   = (const float*)d_in[13];
    const float* bf2   = (const float*)d_in[14];

    const size_t BNH = (size_t)4 * N_ * H_;   // 262144
    float* ws = (float*)d_ws;
    float* h  = ws;
    float* q  = ws + BNH;
    float* k  = ws + 2 * BNH;
    float* v  = ws + 3 * BNH;
    float* x0 = ws + 4 * BNH;
    float* x1 = x0 + (size_t)4 * N_ * 3;

    k_init_h<<<1024, 256, 0, stream>>>(feats, W_in, h);

    const float* xin[3]  = {coors, x0, x1};
    float*       xout[3] = {x0, x1, x0};
    for (int l = 0; l < 3; ++l) {
        k_qkv<<<1024, 256, 0, stream>>>(h, Wq + l * 1024, Wk + l * 1024, Wv + l * 1024, q, k, v);
        k_attn<<<512, 512, 0, stream>>>(q, k, v, h, xin[l], xout[l], adj,
                                        Wo + l * 1024, W1 + l * 2048, W2 + l * 2048,
                                        csc + l);
    }
    k_final<<<4, 256, 0, stream>>>(h, Wf1, bf1, Wf2, bf2, (float*)d_out);
}

// Round 6
// 371.133 us; speedup vs baseline: 1.2363x; 1.2363x over previous
//
#include <hip/hip_runtime.h>
#include <cstddef>

#define N_    2048
#define H_    32
#define NEGF  (-1.0e30f)
#define LOG2E 1.4426950408889634f
#define C1F   (0.17677669529663687f * 1.4426950408889634f)   // (1/sqrt(32))*log2e
#define DEFER 8.0f

#define AS1 __attribute__((address_space(1)))
#define AS3 __attribute__((address_space(3)))

__device__ __forceinline__ float exp2_fast(float x) {
    float r;
    asm("v_exp_f32 %0, %1" : "=v"(r) : "v"(x));
    return r;
}

// ---------------------------------------------------------------- init h
__global__ __launch_bounds__(256) void k_init_h(const float* __restrict__ feats,
                                                const float* __restrict__ W_in,
                                                float* __restrict__ h) {
    int idx = blockIdx.x * 256 + threadIdx.x;       // B*N*32 total
    int bn  = idx >> 5, c = idx & 31;
    float f0 = feats[bn * 3 + 0], f1 = feats[bn * 3 + 1], f2 = feats[bn * 3 + 2];
    h[idx] = f0 * W_in[c] + f1 * W_in[32 + c] + f2 * W_in[64 + c];
}

// ---------------------------------------------------------------- q,k,v
__global__ __launch_bounds__(256) void k_qkv(const float* __restrict__ h,
                                             const float* __restrict__ Wq,
                                             const float* __restrict__ Wk,
                                             const float* __restrict__ Wv,
                                             float* __restrict__ q,
                                             float* __restrict__ k,
                                             float* __restrict__ v) {
    __shared__ float hs[8][33];
    int t = threadIdx.x;
    int rl = t >> 5, c = t & 31;
    int row = blockIdx.x * 8 + rl;
    hs[rl][c] = h[(row << 5) + c];
    __syncthreads();
    float aq = 0.f, ak = 0.f, av = 0.f;
#pragma unroll
    for (int d = 0; d < 32; ++d) {
        float hd = hs[rl][d];
        aq += hd * Wq[(d << 5) + c];
        ak += hd * Wk[(d << 5) + c];
        av += hd * Wv[(d << 5) + c];
    }
    q[(row << 5) + c] = aq;
    k[(row << 5) + c] = ak;
    v[(row << 5) + c] = av;
}

// ---------------------------------------------------------------- fused attention + post + FF
__device__ __forceinline__ void finish_row(float (&acc)[35], float m, float s,
                                           float xi0, float xi1, float xi2,
                                           int lane, int row, float cs,
                                           float* __restrict__ hg,
                                           float* __restrict__ xout,
                                           const float* __restrict__ Wo,
                                           const float* __restrict__ W1,
                                           const float* __restrict__ W2,
                                           float* __restrict__ h1row,
                                           float* __restrict__ frow) {
    // cross-lane online-softmax merge (m is per-lane deferred max, log2 domain)
    float mm = m;
#pragma unroll
    for (int off = 32; off > 0; off >>= 1) mm = fmaxf(mm, __shfl_xor(mm, off));
    float sc = exp2_fast(m - mm);
    float ss = s * sc;
#pragma unroll
    for (int c = 0; c < 35; ++c) acc[c] *= sc;
#pragma unroll
    for (int off = 32; off > 0; off >>= 1) {
        ss += __shfl_xor(ss, off);
#pragma unroll
        for (int c = 0; c < 35; ++c) acc[c] += __shfl_xor(acc[c], off);
    }
    float rinv = 1.0f / ss;
    int rb = row << 5;
    float h1 = 0.f;
    if (lane < 32) {
        float hv = 0.f;
#pragma unroll
        for (int d = 0; d < 32; ++d) hv += acc[d] * Wo[(d << 5) + lane];
        h1 = hg[rb + lane] + hv * rinv;
        h1row[lane] = h1;
    }
    float ff = 0.f;                       // all 64 lanes: FF hidden dim 64
#pragma unroll
    for (int d = 0; d < 32; ++d) ff += h1row[d] * W1[(d << 6) + lane];
    frow[lane] = fmaxf(ff, 0.f);
    if (lane < 32) {
        float v2 = 0.f;
#pragma unroll
        for (int u = 0; u < 64; ++u) v2 += frow[u] * W2[(u << 5) + lane];
        hg[rb + lane] = h1 + v2;
    }
    if (lane < 3) {
        float ox = (lane == 0 ? acc[32] : (lane == 1 ? acc[33] : acc[34])) * rinv;
        float xi = (lane == 0 ? xi0 : (lane == 1 ? xi1 : xi2));
        xout[row * 3 + lane] = xi + cs * (xi - ox);
    }
}

// 8 rows/block, 4 waves of 2 rows. K/V tiles 64x32 double-buffered via
// global_load_lds (linear LDS dest, pre-swizzled global source, offset imm
// ALWAYS 0 -- round-5's nonzero offset imm was the correctness bug suspect).
// __launch_bounds__(256,2): 256-VGPR cap; LDS 67KB -> 2 blocks/CU.
__global__ __launch_bounds__(256, 2) void k_attn(const float* __restrict__ qg,
                                                 const float* __restrict__ kg,
                                                 const float* __restrict__ vg,
                                                 float* __restrict__ hg,
                                                 const float* __restrict__ xin,
                                                 float* __restrict__ xout,
                                                 const int* __restrict__ adj,
                                                 const float* __restrict__ Wo,
                                                 const float* __restrict__ W1,
                                                 const float* __restrict__ W2,
                                                 const float* __restrict__ csp) {
    __shared__ __attribute__((aligned(16))) float tiles[2][2][64 * 32]; // [buf][K/V]
    __shared__ float h1_s[4][33];
    __shared__ float f_s[4][64];

    const int t = threadIdx.x;
    const int w = t >> 6, lane = t & 63;
    const int b  = blockIdx.x >> 8;            // 256 blocks per batch
    const int ib = (blockIdx.x & 255) << 3;    // 8 rows per block
    const int bN = b << 11;
    const int row0 = bN + ib + (w << 1), row1 = row0 + 1;
    const float cs = csp[0];

    // ---- staging geometry: wave w stages rows 16w..16w+15 (two 8-row chunks)
    const int srow   = (w << 4) + (lane >> 3);
    const int schunk = (lane & 7) ^ ((lane >> 3) & 7);
    const float* krun = kg + ((size_t)(bN + srow) << 5) + (schunk << 2);
    const float* vrun = vg + ((size_t)(bN + srow) << 5) + (schunk << 2);
    const int dst0 = w << 11;                  // wave's 2KB dest (byte off in plane)

#define STAGE(BUF)                                                                            \
    do {                                                                                      \
        __builtin_amdgcn_global_load_lds((const AS1 void*)krun,                               \
            (AS3 void*)((char*)&tiles[BUF][0][0] + dst0),        16, 0, 0);                   \
        __builtin_amdgcn_global_load_lds((const AS1 void*)(krun + 256),                       \
            (AS3 void*)((char*)&tiles[BUF][0][0] + dst0 + 1024), 16, 0, 0);                   \
        __builtin_amdgcn_global_load_lds((const AS1 void*)vrun,                               \
            (AS3 void*)((char*)&tiles[BUF][1][0] + dst0),        16, 0, 0);                   \
        __builtin_amdgcn_global_load_lds((const AS1 void*)(vrun + 256),                       \
            (AS3 void*)((char*)&tiles[BUF][1][0] + dst0 + 1024), 16, 0, 0);                   \
        krun += 2048; vrun += 2048;                                                           \
    } while (0)

    // q rows, pre-scaled by (1/sqrt(d))*log2e
    float q0[32], q1[32];
#pragma unroll
    for (int d = 0; d < 32; d += 4) {
        float4 a = *(const float4*)(qg + ((size_t)row0 << 5) + d);
        q0[d] = a.x * C1F; q0[d + 1] = a.y * C1F; q0[d + 2] = a.z * C1F; q0[d + 3] = a.w * C1F;
        float4 b4 = *(const float4*)(qg + ((size_t)row1 << 5) + d);
        q1[d] = b4.x * C1F; q1[d + 1] = b4.y * C1F; q1[d + 2] = b4.z * C1F; q1[d + 3] = b4.w * C1F;
    }
    const float xi00 = xin[row0 * 3 + 0], xi01 = xin[row0 * 3 + 1], xi02 = xin[row0 * 3 + 2];
    const float xi10 = xin[row1 * 3 + 0], xi11 = xin[row1 * 3 + 1], xi12 = xin[row1 * 3 + 2];
    const int* ap0 = adj + (size_t)row0 * N_ + lane;
    const int* ap1 = adj + (size_t)row1 * N_ + lane;
    const float* xp = xin + ((size_t)(bN + lane)) * 3;

    float acc0[35], acc1[35];
#pragma unroll
    for (int c = 0; c < 35; ++c) { acc0[c] = 0.f; acc1[c] = 0.f; }
    float m0 = NEGF, m1 = NEGF, sum0 = 0.f, sum1 = 0.f;

    const int lx    = lane & 7;
    const int lbase = (lane << 7) + (lx << 4);   // byte offset in a tile plane

    // ---- prologue: stage tile 0 + its adj/x
    STAGE(0);
    int a0c = *ap0, a1c = *ap1;
    ap0 += 64; ap1 += 64;
    float xc0 = xp[0], xc1 = xp[1], xc2 = xp[2];
    xp += 192;
    int a0n = 0, a1n = 0;
    float xn0 = 0.f, xn1 = 0.f, xn2 = 0.f;
    __syncthreads();

#define COMPUTE(BUF)                                                                          \
    do {                                                                                      \
        const float xj0 = xc0, xj1 = xc1, xj2 = xc2;                                          \
        float p00 = 0.f, p01 = 0.f, p02 = 0.f, p03 = 0.f;                                     \
        float p10 = 0.f, p11 = 0.f, p12 = 0.f, p13 = 0.f;                                     \
        _Pragma("unroll")                                                                     \
        for (int c = 0; c < 8; ++c) {                                                         \
            float4 k4 = *(const float4*)((const char*)&tiles[BUF][0][0] + (lbase ^ (c << 4)));\
            p00 = fmaf(q0[4 * c],     k4.x, p00);                                             \
            p01 = fmaf(q0[4 * c + 1], k4.y, p01);                                             \
            p02 = fmaf(q0[4 * c + 2], k4.z, p02);                                             \
            p03 = fmaf(q0[4 * c + 3], k4.w, p03);                                             \
            p10 = fmaf(q1[4 * c],     k4.x, p10);                                             \
            p11 = fmaf(q1[4 * c + 1], k4.y, p11);                                             \
            p12 = fmaf(q1[4 * c + 2], k4.z, p12);                                             \
            p13 = fmaf(q1[4 * c + 3], k4.w, p13);                                             \
        }                                                                                     \
        float dot0 = (p00 + p01) + (p02 + p03);                                               \
        float dot1 = (p10 + p11) + (p12 + p13);                                               \
        float d00 = xi00 - xj0, d01 = xi01 - xj1, d02 = xi02 - xj2;                           \
        float d10 = xi10 - xj0, d11 = xi11 - xj1, d12 = xi12 - xj2;                           \
        float t0 = fmaf(d02, d02, fmaf(d01, d01, d00 * d00));                                 \
        float t1 = fmaf(d12, d12, fmaf(d11, d11, d10 * d10));                                 \
        float se0 = a0c ? fmaf(t0, -LOG2E, dot0) : NEGF;                                      \
        float se1 = a1c ? fmaf(t1, -LOG2E, dot1) : NEGF;                                      \
        if (__any(int(se0 - m0 > DEFER) | int(se1 - m1 > DEFER))) {                           \
            float n0 = fmaxf(m0, se0), n1 = fmaxf(m1, se1);                                   \
            float al0 = exp2_fast(m0 - n0), al1 = exp2_fast(m1 - n1);                         \
            m0 = n0; m1 = n1;                                                                 \
            sum0 *= al0; sum1 *= al1;                                                         \
            _Pragma("unroll")                                                                 \
            for (int c = 0; c < 35; ++c) { acc0[c] *= al0; acc1[c] *= al1; }                  \
        }                                                                                     \
        float p0 = exp2_fast(se0 - m0);                                                       \
        float p1 = exp2_fast(se1 - m1);                                                       \
        sum0 += p0; sum1 += p1;                                                               \
        _Pragma("unroll")                                                                     \
        for (int c = 0; c < 8; ++c) {                                                         \
            float4 v4 = *(const float4*)((const char*)&tiles[BUF][1][0] + (lbase ^ (c << 4)));\
            acc0[4 * c]     = fmaf(p0, v4.x, acc0[4 * c]);                                    \
            acc0[4 * c + 1] = fmaf(p0, v4.y, acc0[4 * c + 1]);                                \
            acc0[4 * c + 2] = fmaf(p0, v4.z, acc0[4 * c + 2]);                                \
            acc0[4 * c + 3] = fmaf(p0, v4.w, acc0[4 * c + 3]);                                \
            acc1[4 * c]     = fmaf(p1, v4.x, acc1[4 * c]);                                    \
            acc1[4 * c + 1] = fmaf(p1, v4.y, acc1[4 * c + 1]);                                \
            acc1[4 * c + 2] = fmaf(p1, v4.z, acc1[4 * c + 2]);                                \
            acc1[4 * c + 3] = fmaf(p1, v4.w, acc1[4 * c + 3]);                                \
        }                                                                                     \
        acc0[32] = fmaf(p0, xj0, acc0[32]);                                                   \
        acc0[33] = fmaf(p0, xj1, acc0[33]);                                                   \
        acc0[34] = fmaf(p0, xj2, acc0[34]);                                                   \
        acc1[32] = fmaf(p1, xj0, acc1[32]);                                                   \
        acc1[33] = fmaf(p1, xj1, acc1[33]);                                                   \
        acc1[34] = fmaf(p1, xj2, acc1[34]);                                                   \
    } while (0)

    // unrolled-by-2 double-buffered main loop: 32 tiles of 64 j's
    for (int jt = 0; jt < N_; jt += 128) {
        // even tile (buf 0)
        if (jt + 64 < N_) {
            STAGE(1);
            a0n = *ap0; a1n = *ap1; ap0 += 64; ap1 += 64;
            xn0 = xp[0]; xn1 = xp[1]; xn2 = xp[2]; xp += 192;
        }
        COMPUTE(0);
        __syncthreads();                       // drains staging of buf1
        a0c = a0n; a1c = a1n; xc0 = xn0; xc1 = xn1; xc2 = xn2;
        // odd tile (buf 1)
        if (jt + 128 < N_) {
            STAGE(0);
            a0n = *ap0; a1n = *ap1; ap0 += 64; ap1 += 64;
            xn0 = xp[0]; xn1 = xp[1]; xn2 = xp[2]; xp += 192;
        }
        COMPUTE(1);
        __syncthreads();                       // drains staging of buf0
        a0c = a0n; a1c = a1n; xc0 = xn0; xc1 = xn1; xc2 = xn2;
    }
#undef STAGE
#undef COMPUTE

    finish_row(acc0, m0, sum0, xi00, xi01, xi02, lane, row0, cs,
               hg, xout, Wo, W1, W2, &h1_s[w][0], &f_s[w][0]);
    finish_row(acc1, m1, sum1, xi10, xi11, xi12, lane, row1, cs,
               hg, xout, Wo, W1, W2, &h1_s[w][0], &f_s[w][0]);
}

// ---------------------------------------------------------------- pool + MLP head
__global__ __launch_bounds__(256) void k_final(const float* __restrict__ h,
                                               const float* __restrict__ Wf1,
                                               const float* __restrict__ bf1,
                                               const float* __restrict__ Wf2,
                                               const float* __restrict__ bf2,
                                               float* __restrict__ out) {
    int b = blockIdx.x, t = threadIdx.x;
    int c = t & 31, g = t >> 5;
    float s = 0.f;
    for (int n = g; n < N_; n += 8) s += h[(((b << 11) + n) << 5) + c];
    __shared__ float pool[8][32];
    __shared__ float pooled[32];
    __shared__ float a1[16];
    pool[g][c] = s;
    __syncthreads();
    if (t < 32) {
        float ss = 0.f;
#pragma unroll
        for (int gg = 0; gg < 8; ++gg) ss += pool[gg][t];
        pooled[t] = ss * (1.0f / N_);
    }
    __syncthreads();
    if (t < 16) {
        float a = bf1[t];
#pragma unroll
        for (int d = 0; d < 32; ++d) a += pooled[d] * Wf1[(d << 4) + t];
        a1[t] = fmaxf(a, 0.f);
    }
    __syncthreads();
    if (t < 3) {
        float o = bf2[t];
#pragma unroll
        for (int e = 0; e < 16; ++e) o += a1[e] * Wf2[e * 3 + t];
        out[b * 3 + t] = o;
    }
}

// ---------------------------------------------------------------- launch
extern "C" void kernel_launch(void* const* d_in, const int* in_sizes, int n_in,
                              void* d_out, int out_size, void* d_ws, size_t ws_size,
                              hipStream_t stream) {
    const float* feats = (const float*)d_in[0];
    const float* coors = (const float*)d_in[1];
    const int*   adj   = (const int*)d_in[2];
    const float* W_in  = (const float*)d_in[3];
    const float* Wq    = (const float*)d_in[4];
    const float* Wk    = (const float*)d_in[5];
    const float* Wv    = (const float*)d_in[6];
    const float* Wo    = (const float*)d_in[7];
    const float* W1    = (const float*)d_in[8];
    const float* W2    = (const float*)d_in[9];
    const float* csc   = (const float*)d_in[10];
    const float* Wf1   = (const float*)d_in[11];
    const float* bf1   = (const float*)d_in[12];
    const float* Wf2   = (const float*)d_in[13];
    const float* bf2   = (const float*)d_in[14];

    const size_t BNH = (size_t)4 * N_ * H_;   // 262144
    float* ws = (float*)d_ws;
    float* h  = ws;
    float* q  = ws + BNH;
    float* k  = ws + 2 * BNH;
    float* v  = ws + 3 * BNH;
    float* x0 = ws + 4 * BNH;
    float* x1 = x0 + (size_t)4 * N_ * 3;

    k_init_h<<<1024, 256, 0, stream>>>(feats, W_in, h);

    const float* xin[3]  = {coors, x0, x1};
    float*       xout[3] = {x0, x1, x0};
    for (int l = 0; l < 3; ++l) {
        k_qkv<<<1024, 256, 0, stream>>>(h, Wq + l * 1024, Wk + l * 1024, Wv + l * 1024, q, k, v);
        k_attn<<<1024, 256, 0, stream>>>(q, k, v, h, xin[l], xout[l], adj,
                                         Wo + l * 1024, W1 + l * 2048, W2 + l * 2048,
                                         csc + l);
    }
    k_final<<<4, 256, 0, stream>>>(h, Wf1, bf1, Wf2, bf2, (float*)d_out);
}